// Round 14
// baseline (62231.189 us; speedup 1.0000x reference)
//
#include <hip/hip_runtime.h>

// ---------------------------------------------------------------------------
// GRUNet, round 14: r13 architecture + poller collapse (16K -> 256).
// Seven protocol/compute nulls at 3.1us/step, incl. r4 (weights RESIDENT,
// VGPR=88) = same perf -> neither spill nor protocol is the pacer. Remaining
// invariant: the POLL STORM (16-32K threads hammering MALL). r11's clean
// 0.72us handoff had 2 pollers. Lever: ONE poller thread per WG polls a
// monotonic per-role counter g_cnt[role] (s_sleep backoff); __syncthreads
// broadcasts readiness; 256 threads then do a straight-line batched sc1 read
// of records (guaranteed ready, no polling). Producers: st_sc_v4 records +
// vmcnt(0) + __threadfence + lane0 atomicAdd(g_cnt,1).
// Counter soundness: WG publishes s only after reading s-1 (needs cnt>=32(s-1))
// -> inter-WG spread <=1 step -> cnt = 32(m+1)+k with p_w in {m,m+1}; cnt>=32s
// iff all p_w >= s-1. Records are full-history (no overwrite).
//   role r on XCD r: 32 WGs x 512 thr; roles: 0=gru1.l0(x) 1=gru1.l1(h0s)
//   2=gru2.l0(samples) 3=gru2.l1(q0s)+FC tail.
// ---------------------------------------------------------------------------

typedef unsigned u32x4 __attribute__((ext_vector_type(4)));
typedef _Float16 h2_t  __attribute__((ext_vector_type(2)));

#define S1 8192
#define S2 256

__device__ u32x4 g_h0s[S1][256];   // history records {pair0,pair1,tag,0} (sc1)
__device__ u32x4 g_h1s[S1][256];
__device__ u32x4 g_q0s[S2][256];
__device__ u32x4 g_q1s[S2][256];
__device__ unsigned g_cnt[4];      // monotonic publish counters (1/WG/step)
__device__ int   g_claim[128];     // 4 roles x 32 slices

// ---- f16 pack/unpack ----
__device__ __forceinline__ unsigned pk(float a, float b) {
  unsigned short ua = __builtin_bit_cast(unsigned short, (_Float16)a);
  unsigned short ub = __builtin_bit_cast(unsigned short, (_Float16)b);
  return (unsigned)ua | ((unsigned)ub << 16);
}
__device__ __forceinline__ float unpk(unsigned u, int hi) {
  unsigned short us = (unsigned short)(hi ? (u >> 16) : (u & 0xffffu));
  return (float)__builtin_bit_cast(_Float16, us);
}

#if __has_builtin(__builtin_amdgcn_fdot2)
__device__ __forceinline__ float fdot2(unsigned a, unsigned b, float c) {
  return __builtin_amdgcn_fdot2(__builtin_bit_cast(h2_t, a),
                                __builtin_bit_cast(h2_t, b), c, false);
}
#else
__device__ __forceinline__ float fdot2(unsigned a, unsigned b, float c) {
  h2_t ha = __builtin_bit_cast(h2_t, a), hb = __builtin_bit_cast(h2_t, b);
  return c + (float)ha[0] * (float)hb[0] + (float)ha[1] * (float)hb[1];
}
#endif

// ---- sc1 (MALL-coherent) loads/stores ----
__device__ __forceinline__ u32x4 ld_sc_v4(const u32x4* p) {
  u32x4 v;
  asm volatile("global_load_dwordx4 %0, %1, off sc1\n\t"
               "s_waitcnt vmcnt(0)" : "=&v"(v) : "v"(p) : "memory");
  return v;
}
// 2 loads, one wait: 1 RTT.
__device__ __forceinline__ void ld_sc_2x4(const u32x4* p0, const u32x4* p1,
                                          u32x4& a, u32x4& b) {
  asm volatile("global_load_dwordx4 %0, %2, off sc1\n\t"
               "global_load_dwordx4 %1, %3, off sc1\n\t"
               "s_waitcnt vmcnt(0)"
               : "=&v"(a), "=&v"(b) : "v"(p0), "v"(p1) : "memory");
}
// 4 loads, one wait: 1 RTT.
__device__ __forceinline__ void ld_sc_4x4(const u32x4* p0, const u32x4* p1,
                                          const u32x4* p2, const u32x4* p3,
                                          u32x4& a, u32x4& b, u32x4& c, u32x4& d) {
  asm volatile("global_load_dwordx4 %0, %4, off sc1\n\t"
               "global_load_dwordx4 %1, %5, off sc1\n\t"
               "global_load_dwordx4 %2, %6, off sc1\n\t"
               "global_load_dwordx4 %3, %7, off sc1\n\t"
               "s_waitcnt vmcnt(0)"
               : "=&v"(a), "=&v"(b), "=&v"(c), "=&v"(d)
               : "v"(p0), "v"(p1), "v"(p2), "v"(p3) : "memory");
}
__device__ __forceinline__ void st_sc_v4(u32x4* p, u32x4 v) {
  asm volatile("global_store_dwordx4 %0, %1, off sc1" :: "v"(p), "v"(v) : "memory");
}

// ---- fast activations ----
__device__ __forceinline__ float rcpf(float x) {
#if __has_builtin(__builtin_amdgcn_rcpf)
  return __builtin_amdgcn_rcpf(x);
#else
  return 1.f / x;
#endif
}
__device__ __forceinline__ float sigf(float x) { return rcpf(1.f + __expf(-x)); }
__device__ __forceinline__ float tanh_f(float x) {
  x = fminf(fmaxf(x, -15.f), 15.f);
  const float e = __expf(2.f * x);
  return (e - 1.f) * rcpf(e + 1.f);
}

// ---- LDS swizzles ----
__device__ __forceinline__ int swzHc(int ch) { return ch ^ ((ch >> 3) & 7); }
__device__ __forceinline__ int swzH_pos(int i) { return (swzHc(i >> 2) << 2) | (i & 3); }
__device__ __forceinline__ int swzX_pos(int i) {
  int ch = i >> 2; ch ^= (ch >> 2) & 7; return (ch << 2) | (i & 3);
}

__global__ void init_all() {
  const long long NH = (long long)S1 * 256;
  const long long NQ = (long long)S2 * 256;
  const long long N  = 2 * NH + 2 * NQ;
  u32x4 ff = {0u, 0u, 0xFFFFFFFFu, 0u};
  const long long idx = (long long)blockIdx.x * blockDim.x + threadIdx.x;
  const long long str = (long long)gridDim.x * blockDim.x;
  for (long long k = idx; k < N; k += str) {
    u32x4* r;
    long long k2 = k;
    if (k2 < NH) r = &g_h0s[0][0] + k2;
    else {
      k2 -= NH;
      if (k2 < NH) r = &g_h1s[0][0] + k2;
      else {
        k2 -= NH;
        if (k2 < NQ) r = &g_q0s[0][0] + k2;
        else         r = &g_q1s[0][0] + (k2 - NQ);
      }
    }
    *r = ff;
  }
  if (blockIdx.x == 0) {
    if (threadIdx.x < 128) g_claim[threadIdx.x] = 0;
    if (threadIdx.x < 4)   g_cnt[threadIdx.x] = 0u;
  }
}

__device__ __forceinline__ const u32x4* in_addr(int role, int u, int r) {
  if (role == 1) return &g_h0s[u][r];
  if (role == 2) {
    const int ss = ((u >> 1) << 6) + 63;
    return (u & 1) ? &g_h1s[ss][r] : &g_h0s[ss][r];
  }
  return &g_q0s[u][r];
}
__device__ __forceinline__ unsigned in_want(int role, int u) {
  return (role == 2) ? (unsigned)(((u >> 1) << 6) + 63) : (unsigned)u;
}

#define MAC4(A, W4, H4)                                                       \
  A = fdot2((W4)[0], (H4)[0], A); A = fdot2((W4)[1], (H4)[1], A);             \
  A = fdot2((W4)[2], (H4)[2], A); A = fdot2((W4)[3], (H4)[3], A);

#define RED16(A)                                                              \
  A += __shfl_xor(A, 8, 16); A += __shfl_xor(A, 4, 16);                       \
  A += __shfl_xor(A, 2, 16); A += __shfl_xor(A, 1, 16);

// One wave fetches ALL 256 records of stream step u (4 recs/lane, 1 RTT),
// backoff-repoll until tags match, stage into sIN[u&7].
#define STREAM_FETCH_WAVE(U, LN)                                              \
  {                                                                           \
    const unsigned w = in_want(role, (U));                                    \
    const u32x4* p0 = in_addr(role, (U), 4 * (LN) + 0);                       \
    const u32x4* p1 = in_addr(role, (U), 4 * (LN) + 1);                       \
    const u32x4* p2 = in_addr(role, (U), 4 * (LN) + 2);                       \
    const u32x4* p3 = in_addr(role, (U), 4 * (LN) + 3);                       \
    u32x4 r0, r1, r2, r3;                                                     \
    ld_sc_4x4(p0, p1, p2, p3, r0, r1, r2, r3);                                \
    while (r0[2] != w || r1[2] != w || r2[2] != w || r3[2] != w) {            \
      __builtin_amdgcn_s_sleep(8);                                            \
      ld_sc_4x4(p0, p1, p2, p3, r0, r1, r2, r3);                              \
    }                                                                         \
    unsigned* dst = sIN[(U) & 7];                                             \
    const int b8 = 8 * (LN);                                                  \
    dst[swzH_pos(b8 + 0)] = r0[0]; dst[swzH_pos(b8 + 1)] = r0[1];             \
    dst[swzH_pos(b8 + 2)] = r1[0]; dst[swzH_pos(b8 + 3)] = r1[1];             \
    dst[swzH_pos(b8 + 4)] = r2[0]; dst[swzH_pos(b8 + 5)] = r2[1];             \
    dst[swzH_pos(b8 + 6)] = r3[0]; dst[swzH_pos(b8 + 7)] = r3[1];             \
  }

// One wave fetches the full 512-float x row of step u (8 floats/lane).
#define X_FETCH_WAVE(U, LN)                                                   \
  {                                                                           \
    const float4* xp = (const float4*)(x +                                    \
        (size_t)(((U) & 63) * 128 + ((U) >> 6)) * 512 + 8 * (LN));            \
    float4 a = xp[0], b = xp[1];                                              \
    unsigned* dst = sX[(U) & 7];                                              \
    const int b4 = 4 * (LN);                                                  \
    dst[swzX_pos(b4 + 0)] = pk(a.x, a.y);                                     \
    dst[swzX_pos(b4 + 1)] = pk(a.z, a.w);                                     \
    dst[swzX_pos(b4 + 2)] = pk(b.x, b.y);                                     \
    dst[swzX_pos(b4 + 3)] = pk(b.z, b.w);                                     \
  }

__global__
__attribute__((amdgpu_flat_work_group_size(512, 512), amdgpu_waves_per_eu(2, 2)))
void gru_all(const float* __restrict__ x,
             const float* __restrict__ g1_Wi0, const float* __restrict__ g1_Wh0,
             const float* __restrict__ g1_bi0, const float* __restrict__ g1_bh0,
             const float* __restrict__ g1_Wi1, const float* __restrict__ g1_Wh1,
             const float* __restrict__ g1_bi1, const float* __restrict__ g1_bh1,
             const float* __restrict__ g2_Wi0, const float* __restrict__ g2_Wh0,
             const float* __restrict__ g2_bi0, const float* __restrict__ g2_bh0,
             const float* __restrict__ g2_Wi1, const float* __restrict__ g2_Wh1,
             const float* __restrict__ g2_bi1, const float* __restrict__ g2_bh1,
             const float* __restrict__ fc1W, const float* __restrict__ fc1b,
             const float* __restrict__ fc2W, const float* __restrict__ fc2b,
             float* __restrict__ out)
{
  const int tid = threadIdx.x;
  const int G   = tid >> 4;            // 32 groups of 16 lanes
  const int q   = tid & 15;
  const int sw  = (tid >> 6) - 4;      // stream-wave id 0..3 (tid>=256)
  const int ln  = tid & 63;            // lane in wave
  const int rid = tid - 256;

  __shared__ __attribute__((aligned(16))) unsigned sH[2][512];   // own h[s-1]
  __shared__ __attribute__((aligned(16))) unsigned sIN[8][512];  // stream ring
  __shared__ __attribute__((aligned(16))) unsigned sX[8][256];   // x ring (role0)
  __shared__ float sD[96];             // Wh row dots
  __shared__ float sDI[96];            // Wi row dots
  __shared__ float sY[128];
  __shared__ int   sSlot;

  // ---- slot claim: prefer own-XCD role; bounded global fallback ----
  unsigned xcc;
  asm volatile("s_getreg_b32 %0, hwreg(HW_REG_XCC_ID)" : "=s"(xcc));
  xcc &= 7u;
  if (tid == 0) {
    int slot = -1;
    if (xcc < 4u) {
      for (int i = 0; i < 32 && slot < 0; ++i)
        if (atomicCAS(&g_claim[(int)xcc * 32 + i], 0, 1) == 0)
          slot = (int)xcc * 32 + i;
    }
    if (slot < 0) {
      for (int k = 0; k < 32; ++k) __builtin_amdgcn_s_sleep(64);  // ~60us
      for (int i = 0; i < 128 && slot < 0; ++i)
        if (atomicCAS(&g_claim[i], 0, 1) == 0) slot = i;
    }
    sSlot = slot;
  }
  __syncthreads();
  const int slot = sSlot;
  if (slot < 0) return;                // surplus WG
  const int role = slot >> 5;          // 0..3
  const int rank = slot & 31;          // h-slice [32*rank, +32)
  const int e0   = rank * 32;
  const int S    = (role <= 1) ? S1 : S2;

  const float* Wh  = (role == 0) ? g1_Wh0 : (role == 1) ? g1_Wh1
                   : (role == 2) ? g2_Wh0 : g2_Wh1;
  const float* Wi  = (role == 0) ? g1_Wi0 : (role == 1) ? g1_Wi1
                   : (role == 2) ? g2_Wi0 : g2_Wi1;
  const float* pbi = (role == 0) ? g1_bi0 : (role == 1) ? g1_bi1
                   : (role == 2) ? g2_bi0 : g2_bi1;
  const float* pbh = (role == 0) ? g1_bh0 : (role == 1) ? g1_bh1
                   : (role == 2) ? g2_bh0 : g2_bh1;
  u32x4 (*outA)[256] = (role == 0) ? g_h0s : (role == 1) ? g_h1s
                     : (role == 2) ? g_q0s : g_q1s;

  // ---- weights -> registers/scratch (r4 proved resident-vs-spill is not the
  //      pacer; keep the simple 6-rows-per-group layout) ----
  u32x4 wv[6][8];
  {
    const bool isWh = (G < 16);
    const int  Gm   = isWh ? G : (G - 16);
    const float* M  = isWh ? Wh : Wi;
    const bool wide = isWh || (role != 0);
    #pragma unroll
    for (int j = 0; j < 6; ++j) {
      const int rr = Gm * 6 + j;
      const int R  = (rr >> 5) * 1024 + e0 + (rr & 31);
      if (wide) {
        const float4* rp = (const float4*)(M + (size_t)R * 1024 + 64 * q);
        #pragma unroll
        for (int c = 0; c < 8; ++c) {
          float4 a = rp[2 * c], b = rp[2 * c + 1];
          wv[j][c] = (u32x4){pk(a.x, a.y), pk(a.z, a.w), pk(b.x, b.y), pk(b.z, b.w)};
        }
      } else {
        const float4* rp = (const float4*)(M + (size_t)R * 512 + 32 * q);
        #pragma unroll
        for (int c = 0; c < 4; ++c) {
          float4 a = rp[2 * c], b = rp[2 * c + 1];
          wv[j][c] = (u32x4){pk(a.x, a.y), pk(a.z, a.w), pk(b.x, b.y), pk(b.z, b.w)};
        }
      }
    }
  }

  // ---- biases for combine lanes (tid<32 -> elem e0+tid) ----
  float bIr = 0, bIz = 0, bIn = 0, bHr = 0, bHz = 0, bHn = 0;
  if (tid < 32) {
    const int ge = e0 + tid;
    bIr = pbi[ge]; bIz = pbi[1024 + ge]; bIn = pbi[2048 + ge];
    bHr = pbh[ge]; bHz = pbh[1024 + ge]; bHn = pbh[2048 + ge];
  }

  // ---- stream prologue: wave 4+k fetches step k ----
  if (tid >= 256) {
    const int u = sw;                  // 0..3 (< S always)
    if (role == 0) { X_FETCH_WAVE(u, ln); }
    else           { STREAM_FETCH_WAVE(u, ln); }
  }
  __syncthreads();

  // =======================  serial scan  =======================
  for (int s = 0; s < S; ++s) {
    const int par = s & 1;

    // ---- stream batch-fetch: wave 4+k owns step s+4+k ----
    if (tid >= 256 && (s & 3) == 0) {
      const int u = s + 4 + sw;
      if (u < S) {
        if (role == 0) { X_FETCH_WAVE(u, ln); }
        else           { STREAM_FETCH_WAVE(u, ln); }
      }
    }

    // ---- readiness: ONE poller thread on the role counter ----
    if (tid == 0 && s > 0) {
      const unsigned want = 32u * (unsigned)s;
      unsigned c = atomicAdd(&g_cnt[role], 0u);
      while (c < want) {
        __builtin_amdgcn_s_sleep(2);
        c = atomicAdd(&g_cnt[role], 0u);
      }
    }
    __syncthreads();                                   // barrier 0 (broadcast)

    // ---- straight-line batched record read (guaranteed ready) ----
    if (tid < 256) {
      unsigned d0 = 0, d1 = 0, d2 = 0, d3 = 0;
      if (s > 0) {
        const u32x4* a0 = &outA[s - 1][2 * (tid & 127)];
        const u32x4* a1 = a0 + 1;
        u32x4 r0, r1;
        ld_sc_2x4(a0, a1, r0, r1);
        // tid 0..127 stage records 0..255 pairwise; tid 128..255 mirror upper
        if (tid < 128) { d0 = r0[0]; d1 = r0[1]; d2 = r1[0]; d3 = r1[1]; }
        else           { d0 = r0[0]; d1 = r0[1]; d2 = r1[0]; d3 = r1[1]; }
        const int base = 4 * (tid & 127);
        if (tid < 128) {
          sH[par][swzH_pos(base + 0)] = d0;
          sH[par][swzH_pos(base + 1)] = d1;
          sH[par][swzH_pos(base + 2)] = d2;
          sH[par][swzH_pos(base + 3)] = d3;
        }
        // tid 128..255: redundant read (keeps load balanced); no store
      } else if (tid < 128) {
        const int base = 4 * tid;
        sH[par][swzH_pos(base + 0)] = 0u;
        sH[par][swzH_pos(base + 1)] = 0u;
        sH[par][swzH_pos(base + 2)] = 0u;
        sH[par][swzH_pos(base + 3)] = 0u;
      }
    }
    __syncthreads();                                   // barrier 1

    // ---- row dots (register weights x LDS operand) ----
    float a0 = 0, a1 = 0, a2 = 0, a3 = 0, a4 = 0, a5 = 0;
    if (G < 16) {                                      // Wh groups: h[s-1]
      const u32x4* HV = (const u32x4*)sH[par];
      #pragma unroll
      for (int c = 0; c < 8; ++c) {
        const u32x4 h4 = HV[8 * q + (c ^ (q & 7))];
        MAC4(a0, wv[0][c], h4); MAC4(a1, wv[1][c], h4); MAC4(a2, wv[2][c], h4);
        MAC4(a3, wv[3][c], h4); MAC4(a4, wv[4][c], h4); MAC4(a5, wv[5][c], h4);
      }
    } else if (role != 0) {                            // Wi groups: stream
      const u32x4* IV = (const u32x4*)sIN[s & 7];
      #pragma unroll
      for (int c = 0; c < 8; ++c) {
        const u32x4 h4 = IV[8 * q + (c ^ (q & 7))];
        MAC4(a0, wv[0][c], h4); MAC4(a1, wv[1][c], h4); MAC4(a2, wv[2][c], h4);
        MAC4(a3, wv[3][c], h4); MAC4(a4, wv[4][c], h4); MAC4(a5, wv[5][c], h4);
      }
    } else {                                           // role0 Wi: x (512 col)
      const u32x4* XV = (const u32x4*)sX[s & 7];
      #pragma unroll
      for (int c = 0; c < 4; ++c) {
        const int ch = 4 * q + c;
        const u32x4 h4 = XV[ch ^ ((ch >> 2) & 7)];
        MAC4(a0, wv[0][c], h4); MAC4(a1, wv[1][c], h4); MAC4(a2, wv[2][c], h4);
        MAC4(a3, wv[3][c], h4); MAC4(a4, wv[4][c], h4); MAC4(a5, wv[5][c], h4);
      }
    }
    RED16(a0); RED16(a1); RED16(a2); RED16(a3); RED16(a4); RED16(a5);
    if (q < 6) {
      const float v = (q == 0) ? a0 : (q == 1) ? a1 : (q == 2) ? a2
                    : (q == 3) ? a3 : (q == 4) ? a4 : a5;
      if (G < 16) sD[G * 6 + q] = v;
      else        sDI[(G - 16) * 6 + q] = v;
    }
    __syncthreads();                                   // barrier 2

    // ---- gate combine + publish (lanes 0..31 of wave 0) ----
    if (tid < 32) {
      const float rg = sigf(sDI[tid] + bIr + sD[tid] + bHr);
      const float zg = sigf(sDI[32 + tid] + bIz + sD[32 + tid] + bHz);
      const float ng = tanh_f(sDI[64 + tid] + bIn + rg * (sD[64 + tid] + bHn));
      const int ge = e0 + tid;
      const float hp = unpk(sH[par][swzH_pos(ge >> 1)], ge & 1);
      const float hn = (1.f - zg) * ng + zg * hp;
      // shuffles with all 32 source lanes active (r8-proven); store guarded.
      const int b4 = (tid & 7) * 4;
      const float v0 = __shfl(hn, b4),     v1 = __shfl(hn, b4 + 1);
      const float v2 = __shfl(hn, b4 + 2), v3 = __shfl(hn, b4 + 3);
      if (tid < 8) {
        u32x4 rec = {pk(v0, v1), pk(v2, v3), (unsigned)s, 0u};
        st_sc_v4(&outA[s][rank * 8 + tid], rec);
      }
      // release: wave-0 store drain + device fence + counter bump
      asm volatile("s_waitcnt vmcnt(0)" ::: "memory");
      __threadfence();
      if (tid == 0) atomicAdd(&g_cnt[role], 1u);
    }
    // next iter's barrier0 orders all buffer reuse
  }

  // =======================  FC tail (role 3, rank 0)  ========================
  if (role == 3 && rank == 0) {
    if (tid < 256) {                    // h2_0[255] -> sH[0]
      const u32x4* a = &g_q0s[S2 - 1][tid];
      u32x4 r = ld_sc_v4(a);
      while (r[2] != (unsigned)(S2 - 1)) { __builtin_amdgcn_s_sleep(8); r = ld_sc_v4(a); }
      sH[0][swzH_pos(2 * tid)]     = r[0];
      sH[0][swzH_pos(2 * tid + 1)] = r[1];
    } else {                            // h2_1[255] -> sH[1]
      const u32x4* a = &g_q1s[S2 - 1][rid];
      u32x4 r = ld_sc_v4(a);
      while (r[2] != (unsigned)(S2 - 1)) { __builtin_amdgcn_s_sleep(8); r = ld_sc_v4(a); }
      sH[1][swzH_pos(2 * rid)]     = r[0];
      sH[1][swzH_pos(2 * rid + 1)] = r[1];
    }
    __syncthreads();
    if (tid < 128) {
      const int l = tid >> 6, k = tid & 63;
      const unsigned* Hs = (const unsigned*)sH[l];
      const float* wrow = fc1W + (size_t)k * 1024;
      float acc = fc1b[k];
      for (int j2 = 0; j2 < 512; ++j2) {
        const unsigned hu = Hs[swzH_pos(j2)];
        acc += unpk(hu, 0) * wrow[2 * j2] + unpk(hu, 1) * wrow[2 * j2 + 1];
      }
      sY[tid] = sigf(acc);
    }
    __syncthreads();
    if (tid < 2) {
      const float* yv = sY + tid * 64;
      float acc = fc2b[0];
      for (int k2 = 0; k2 < 64; ++k2) acc += fc2W[k2] * yv[k2];
      out[tid] = sigf(acc);
    }
  }
}

extern "C" void kernel_launch(void* const* d_in, const int* in_sizes, int n_in,
                              void* d_out, int out_size, void* d_ws, size_t ws_size,
                              hipStream_t stream) {
  (void)in_sizes; (void)n_in; (void)out_size; (void)d_ws; (void)ws_size;
  const float* x      = (const float*)d_in[0];
  const float* g1_Wi0 = (const float*)d_in[1];
  const float* g1_Wh0 = (const float*)d_in[2];
  const float* g1_bi0 = (const float*)d_in[3];
  const float* g1_bh0 = (const float*)d_in[4];
  const float* g1_Wi1 = (const float*)d_in[5];
  const float* g1_Wh1 = (const float*)d_in[6];
  const float* g1_bi1 = (const float*)d_in[7];
  const float* g1_bh1 = (const float*)d_in[8];
  const float* g2_Wi0 = (const float*)d_in[9];
  const float* g2_Wh0 = (const float*)d_in[10];
  const float* g2_bi0 = (const float*)d_in[11];
  const float* g2_bh0 = (const float*)d_in[12];
  const float* g2_Wi1 = (const float*)d_in[13];
  const float* g2_Wh1 = (const float*)d_in[14];
  const float* g2_bi1 = (const float*)d_in[15];
  const float* g2_bh1 = (const float*)d_in[16];
  const float* fc1W   = (const float*)d_in[17];
  const float* fc1b   = (const float*)d_in[18];
  const float* fc2W   = (const float*)d_in[19];
  const float* fc2b   = (const float*)d_in[20];
  float* out = (float*)d_out;

  init_all<<<dim3(2048), dim3(256), 0, stream>>>();
  gru_all<<<dim3(256), dim3(512), 0, stream>>>(
      x, g1_Wi0, g1_Wh0, g1_bi0, g1_bh0, g1_Wi1, g1_Wh1, g1_bi1, g1_bh1,
      g2_Wi0, g2_Wh0, g2_bi0, g2_bh0, g2_Wi1, g2_Wh1, g2_bi1, g2_bh1,
      fc1W, fc1b, fc2W, fc2b, out);
}

// Round 15
// 29420.291 us; speedup vs baseline: 2.1152x; 2.1152x over previous
//
#include <hip/hip_runtime.h>

// ---------------------------------------------------------------------------
// GRUNet, round 15: r13 base + pipelined non-blocking recurrence poll.
// Latency model (r8-r14 evidence): step = publish one-way (~0.6us) +
// DISCOVERY GRANULARITY + return (~0.75us) + compute (~0.4us). All prior
// variants polled with blocking vmcnt(0) loads -> granularity = full RTT
// (~1.5us) -> tau ~3.1us. Lever: one wave/WG polls all 256 records (4/lane)
// with 4 loads in flight; loop = wait vmcnt(3) -> sched_barrier(0) -> check
// oldest tag -> UNCONDITIONAL reissue (records immutable once written, so
// re-loading after tag-match returns identical data). Sampling period drops
// to the ~40-80ns loop slot. Exit via __all; vmcnt(0) drain leaves r0..r3
// valid. g_fast atomics deleted (r12 null, contention).
//   role r on XCD r: 32 WGs x 512 thr; roles: 0=gru1.l0(x) 1=gru1.l1(h0s)
//   2=gru2.l0(samples) 3=gru2.l1(q0s)+FC tail.
// ---------------------------------------------------------------------------

typedef unsigned u32x4 __attribute__((ext_vector_type(4)));
typedef _Float16 h2_t  __attribute__((ext_vector_type(2)));

#define S1 8192
#define S2 256

__device__ u32x4 g_h0s[S1][256];   // records {pair0,pair1,tag,0} (sc1, write-once)
__device__ u32x4 g_h1s[S1][256];
__device__ u32x4 g_q0s[S2][256];
__device__ u32x4 g_q1s[S2][256];
__device__ int   g_claim[128];     // 4 roles x 32 slices

// ---- f16 pack/unpack ----
__device__ __forceinline__ unsigned pk(float a, float b) {
  unsigned short ua = __builtin_bit_cast(unsigned short, (_Float16)a);
  unsigned short ub = __builtin_bit_cast(unsigned short, (_Float16)b);
  return (unsigned)ua | ((unsigned)ub << 16);
}
__device__ __forceinline__ float unpk(unsigned u, int hi) {
  unsigned short us = (unsigned short)(hi ? (u >> 16) : (u & 0xffffu));
  return (float)__builtin_bit_cast(_Float16, us);
}

#if __has_builtin(__builtin_amdgcn_fdot2)
__device__ __forceinline__ float fdot2(unsigned a, unsigned b, float c) {
  return __builtin_amdgcn_fdot2(__builtin_bit_cast(h2_t, a),
                                __builtin_bit_cast(h2_t, b), c, false);
}
#else
__device__ __forceinline__ float fdot2(unsigned a, unsigned b, float c) {
  h2_t ha = __builtin_bit_cast(h2_t, a), hb = __builtin_bit_cast(h2_t, b);
  return c + (float)ha[0] * (float)hb[0] + (float)ha[1] * (float)hb[1];
}
#endif

// ---- sc1 (MALL-coherent) loads/stores ----
__device__ __forceinline__ u32x4 ld_sc_v4(const u32x4* p) {
  u32x4 v;
  asm volatile("global_load_dwordx4 %0, %1, off sc1\n\t"
               "s_waitcnt vmcnt(0)" : "=&v"(v) : "v"(p) : "memory");
  return v;
}
// 4 loads, one wait: 1 RTT (stream fetch).
__device__ __forceinline__ void ld_sc_4x4(const u32x4* p0, const u32x4* p1,
                                          const u32x4* p2, const u32x4* p3,
                                          u32x4& a, u32x4& b, u32x4& c, u32x4& d) {
  asm volatile("global_load_dwordx4 %0, %4, off sc1\n\t"
               "global_load_dwordx4 %1, %5, off sc1\n\t"
               "global_load_dwordx4 %2, %6, off sc1\n\t"
               "global_load_dwordx4 %3, %7, off sc1\n\t"
               "s_waitcnt vmcnt(0)"
               : "=&v"(a), "=&v"(b), "=&v"(c), "=&v"(d)
               : "v"(p0), "v"(p1), "v"(p2), "v"(p3) : "memory");
}
__device__ __forceinline__ void st_sc_v4(u32x4* p, u32x4 v) {
  asm volatile("global_store_dwordx4 %0, %1, off sc1" :: "v"(p), "v"(v) : "memory");
}

// ---- fast activations ----
__device__ __forceinline__ float rcpf(float x) {
#if __has_builtin(__builtin_amdgcn_rcpf)
  return __builtin_amdgcn_rcpf(x);
#else
  return 1.f / x;
#endif
}
__device__ __forceinline__ float sigf(float x) { return rcpf(1.f + __expf(-x)); }
__device__ __forceinline__ float tanh_f(float x) {
  x = fminf(fmaxf(x, -15.f), 15.f);
  const float e = __expf(2.f * x);
  return (e - 1.f) * rcpf(e + 1.f);
}

// ---- LDS swizzles ----
__device__ __forceinline__ int swzHc(int ch) { return ch ^ ((ch >> 3) & 7); }
__device__ __forceinline__ int swzH_pos(int i) { return (swzHc(i >> 2) << 2) | (i & 3); }
__device__ __forceinline__ int swzX_pos(int i) {
  int ch = i >> 2; ch ^= (ch >> 2) & 7; return (ch << 2) | (i & 3);
}

__global__ void init_all() {
  const long long NH = (long long)S1 * 256;
  const long long NQ = (long long)S2 * 256;
  const long long N  = 2 * NH + 2 * NQ;
  u32x4 ff = {0u, 0u, 0xFFFFFFFFu, 0u};
  const long long idx = (long long)blockIdx.x * blockDim.x + threadIdx.x;
  const long long str = (long long)gridDim.x * blockDim.x;
  for (long long k = idx; k < N; k += str) {
    u32x4* r;
    long long k2 = k;
    if (k2 < NH) r = &g_h0s[0][0] + k2;
    else {
      k2 -= NH;
      if (k2 < NH) r = &g_h1s[0][0] + k2;
      else {
        k2 -= NH;
        if (k2 < NQ) r = &g_q0s[0][0] + k2;
        else         r = &g_q1s[0][0] + (k2 - NQ);
      }
    }
    *r = ff;
  }
  if (blockIdx.x == 0 && threadIdx.x < 128) g_claim[threadIdx.x] = 0;
}

__device__ __forceinline__ const u32x4* in_addr(int role, int u, int r) {
  if (role == 1) return &g_h0s[u][r];
  if (role == 2) {
    const int ss = ((u >> 1) << 6) + 63;
    return (u & 1) ? &g_h1s[ss][r] : &g_h0s[ss][r];
  }
  return &g_q0s[u][r];
}
__device__ __forceinline__ unsigned in_want(int role, int u) {
  return (role == 2) ? (unsigned)(((u >> 1) << 6) + 63) : (unsigned)u;
}

#define MAC4(A, W4, H4)                                                       \
  A = fdot2((W4)[0], (H4)[0], A); A = fdot2((W4)[1], (H4)[1], A);             \
  A = fdot2((W4)[2], (H4)[2], A); A = fdot2((W4)[3], (H4)[3], A);

#define RED16(A)                                                              \
  A += __shfl_xor(A, 8, 16); A += __shfl_xor(A, 4, 16);                       \
  A += __shfl_xor(A, 2, 16); A += __shfl_xor(A, 1, 16);

// One wave fetches ALL 256 records of stream step u (4 recs/lane, 1 RTT),
// backoff-repoll until tags match, stage into sIN[u&7]. Off critical path.
#define STREAM_FETCH_WAVE(U, LN)                                              \
  {                                                                           \
    const unsigned w = in_want(role, (U));                                    \
    const u32x4* p0 = in_addr(role, (U), 4 * (LN) + 0);                       \
    const u32x4* p1 = in_addr(role, (U), 4 * (LN) + 1);                       \
    const u32x4* p2 = in_addr(role, (U), 4 * (LN) + 2);                       \
    const u32x4* p3 = in_addr(role, (U), 4 * (LN) + 3);                       \
    u32x4 r0, r1, r2, r3;                                                     \
    ld_sc_4x4(p0, p1, p2, p3, r0, r1, r2, r3);                                \
    while (r0[2] != w || r1[2] != w || r2[2] != w || r3[2] != w) {            \
      __builtin_amdgcn_s_sleep(8);                                            \
      ld_sc_4x4(p0, p1, p2, p3, r0, r1, r2, r3);                              \
    }                                                                         \
    unsigned* dst = sIN[(U) & 7];                                             \
    const int b8 = 8 * (LN);                                                  \
    dst[swzH_pos(b8 + 0)] = r0[0]; dst[swzH_pos(b8 + 1)] = r0[1];             \
    dst[swzH_pos(b8 + 2)] = r1[0]; dst[swzH_pos(b8 + 3)] = r1[1];             \
    dst[swzH_pos(b8 + 4)] = r2[0]; dst[swzH_pos(b8 + 5)] = r2[1];             \
    dst[swzH_pos(b8 + 6)] = r3[0]; dst[swzH_pos(b8 + 7)] = r3[1];             \
  }

// One wave fetches the full 512-float x row of step u (8 floats/lane).
#define X_FETCH_WAVE(U, LN)                                                   \
  {                                                                           \
    const float4* xp = (const float4*)(x +                                    \
        (size_t)(((U) & 63) * 128 + ((U) >> 6)) * 512 + 8 * (LN));            \
    float4 a = xp[0], b = xp[1];                                              \
    unsigned* dst = sX[(U) & 7];                                              \
    const int b4 = 4 * (LN);                                                  \
    dst[swzX_pos(b4 + 0)] = pk(a.x, a.y);                                     \
    dst[swzX_pos(b4 + 1)] = pk(a.z, a.w);                                     \
    dst[swzX_pos(b4 + 2)] = pk(b.x, b.y);                                     \
    dst[swzX_pos(b4 + 3)] = pk(b.z, b.w);                                     \
  }

__global__
__attribute__((amdgpu_flat_work_group_size(512, 512), amdgpu_waves_per_eu(2, 2)))
void gru_all(const float* __restrict__ x,
             const float* __restrict__ g1_Wi0, const float* __restrict__ g1_Wh0,
             const float* __restrict__ g1_bi0, const float* __restrict__ g1_bh0,
             const float* __restrict__ g1_Wi1, const float* __restrict__ g1_Wh1,
             const float* __restrict__ g1_bi1, const float* __restrict__ g1_bh1,
             const float* __restrict__ g2_Wi0, const float* __restrict__ g2_Wh0,
             const float* __restrict__ g2_bi0, const float* __restrict__ g2_bh0,
             const float* __restrict__ g2_Wi1, const float* __restrict__ g2_Wh1,
             const float* __restrict__ g2_bi1, const float* __restrict__ g2_bh1,
             const float* __restrict__ fc1W, const float* __restrict__ fc1b,
             const float* __restrict__ fc2W, const float* __restrict__ fc2b,
             float* __restrict__ out)
{
  const int tid = threadIdx.x;
  const int G   = tid >> 4;            // 32 groups of 16 lanes
  const int q   = tid & 15;
  const int sw  = (tid >> 6) - 4;      // stream-wave id 0..3 (tid>=256)
  const int ln  = tid & 63;            // lane in wave
  const int rid = tid - 256;

  __shared__ __attribute__((aligned(16))) unsigned sH[2][512];   // own h[s-1]
  __shared__ __attribute__((aligned(16))) unsigned sIN[8][512];  // stream ring
  __shared__ __attribute__((aligned(16))) unsigned sX[8][256];   // x ring (role0)
  __shared__ float sD[96];             // Wh row dots
  __shared__ float sDI[96];            // Wi row dots
  __shared__ float sY[128];
  __shared__ int   sSlot;

  // ---- slot claim: prefer own-XCD role; bounded global fallback ----
  unsigned xcc;
  asm volatile("s_getreg_b32 %0, hwreg(HW_REG_XCC_ID)" : "=s"(xcc));
  xcc &= 7u;
  if (tid == 0) {
    int slot = -1;
    if (xcc < 4u) {
      for (int i = 0; i < 32 && slot < 0; ++i)
        if (atomicCAS(&g_claim[(int)xcc * 32 + i], 0, 1) == 0)
          slot = (int)xcc * 32 + i;
    }
    if (slot < 0) {
      for (int k = 0; k < 32; ++k) __builtin_amdgcn_s_sleep(64);  // ~60us
      for (int i = 0; i < 128 && slot < 0; ++i)
        if (atomicCAS(&g_claim[i], 0, 1) == 0) slot = i;
    }
    sSlot = slot;
  }
  __syncthreads();
  const int slot = sSlot;
  if (slot < 0) return;                // surplus WG
  const int role = slot >> 5;          // 0..3
  const int rank = slot & 31;          // h-slice [32*rank, +32)
  const int e0   = rank * 32;
  const int S    = (role <= 1) ? S1 : S2;

  const float* Wh  = (role == 0) ? g1_Wh0 : (role == 1) ? g1_Wh1
                   : (role == 2) ? g2_Wh0 : g2_Wh1;
  const float* Wi  = (role == 0) ? g1_Wi0 : (role == 1) ? g1_Wi1
                   : (role == 2) ? g2_Wi0 : g2_Wi1;
  const float* pbi = (role == 0) ? g1_bi0 : (role == 1) ? g1_bi1
                   : (role == 2) ? g2_bi0 : g2_bi1;
  const float* pbh = (role == 0) ? g1_bh0 : (role == 1) ? g1_bh1
                   : (role == 2) ? g2_bh0 : g2_bh1;
  u32x4 (*outA)[256] = (role == 0) ? g_h0s : (role == 1) ? g_h1s
                     : (role == 2) ? g_q0s : g_q1s;

  // ---- weights (r4 proved resident-vs-spill not the pacer; keep layout) ----
  u32x4 wv[6][8];
  {
    const bool isWh = (G < 16);
    const int  Gm   = isWh ? G : (G - 16);
    const float* M  = isWh ? Wh : Wi;
    const bool wide = isWh || (role != 0);
    #pragma unroll
    for (int j = 0; j < 6; ++j) {
      const int rr = Gm * 6 + j;
      const int R  = (rr >> 5) * 1024 + e0 + (rr & 31);
      if (wide) {
        const float4* rp = (const float4*)(M + (size_t)R * 1024 + 64 * q);
        #pragma unroll
        for (int c = 0; c < 8; ++c) {
          float4 a = rp[2 * c], b = rp[2 * c + 1];
          wv[j][c] = (u32x4){pk(a.x, a.y), pk(a.z, a.w), pk(b.x, b.y), pk(b.z, b.w)};
        }
      } else {
        const float4* rp = (const float4*)(M + (size_t)R * 512 + 32 * q);
        #pragma unroll
        for (int c = 0; c < 4; ++c) {
          float4 a = rp[2 * c], b = rp[2 * c + 1];
          wv[j][c] = (u32x4){pk(a.x, a.y), pk(a.z, a.w), pk(b.x, b.y), pk(b.z, b.w)};
        }
      }
    }
  }

  // ---- biases for combine lanes (tid<32 -> elem e0+tid) ----
  float bIr = 0, bIz = 0, bIn = 0, bHr = 0, bHz = 0, bHn = 0;
  if (tid < 32) {
    const int ge = e0 + tid;
    bIr = pbi[ge]; bIz = pbi[1024 + ge]; bIn = pbi[2048 + ge];
    bHr = pbh[ge]; bHz = pbh[1024 + ge]; bHn = pbh[2048 + ge];
  }

  // ---- stream prologue: wave 4+k fetches step k ----
  if (tid >= 256) {
    const int u = sw;                  // 0..3 (< S always)
    if (role == 0) { X_FETCH_WAVE(u, ln); }
    else           { STREAM_FETCH_WAVE(u, ln); }
  }
  __syncthreads();

  // =======================  serial scan  =======================
  for (int s = 0; s < S; ++s) {
    const int par = s & 1;

    // ---- stream batch-fetch: wave 4+k owns step s+4+k ----
    if (tid >= 256 && (s & 3) == 0) {
      const int u = s + 4 + sw;
      if (u < S) {
        if (role == 0) { X_FETCH_WAVE(u, ln); }
        else           { STREAM_FETCH_WAVE(u, ln); }
      }
    }

    // ---- recurrence: pipelined 4-slot tag-poll (wave 0; 4 recs/lane) ----
    if (tid < 64) {
      if (s > 0) {
        const unsigned w = (unsigned)(s - 1);
        const u32x4* p0 = &outA[s - 1][4 * tid + 0];
        const u32x4* p1 = &outA[s - 1][4 * tid + 1];
        const u32x4* p2 = &outA[s - 1][4 * tid + 2];
        const u32x4* p3 = &outA[s - 1][4 * tid + 3];
        u32x4 r0, r1, r2, r3;
        asm volatile("global_load_dwordx4 %0, %4, off sc1\n\t"
                     "global_load_dwordx4 %1, %5, off sc1\n\t"
                     "global_load_dwordx4 %2, %6, off sc1\n\t"
                     "global_load_dwordx4 %3, %7, off sc1"
                     : "=&v"(r0), "=&v"(r1), "=&v"(r2), "=&v"(r3)
                     : "v"(p0), "v"(p1), "v"(p2), "v"(p3) : "memory");
        bool done = false;
        while (!done) {
          // slot 0: wait oldest, check, unconditional reissue (immutable recs)
          asm volatile("s_waitcnt vmcnt(3)" ::: "memory");
          __builtin_amdgcn_sched_barrier(0);
          const bool k0 = (r0[2] == w);
          asm volatile("global_load_dwordx4 %0, %1, off sc1"
                       : "=&v"(r0) : "v"(p0) : "memory");
          asm volatile("s_waitcnt vmcnt(3)" ::: "memory");
          __builtin_amdgcn_sched_barrier(0);
          const bool k1 = (r1[2] == w);
          asm volatile("global_load_dwordx4 %0, %1, off sc1"
                       : "=&v"(r1) : "v"(p1) : "memory");
          asm volatile("s_waitcnt vmcnt(3)" ::: "memory");
          __builtin_amdgcn_sched_barrier(0);
          const bool k2 = (r2[2] == w);
          asm volatile("global_load_dwordx4 %0, %1, off sc1"
                       : "=&v"(r2) : "v"(p2) : "memory");
          asm volatile("s_waitcnt vmcnt(3)" ::: "memory");
          __builtin_amdgcn_sched_barrier(0);
          const bool k3 = (r3[2] == w);
          asm volatile("global_load_dwordx4 %0, %1, off sc1"
                       : "=&v"(r3) : "v"(p3) : "memory");
          done = __all(k0 && k1 && k2 && k3);
        }
        // drain: newest loads sampled after tags matched -> valid (immutable)
        asm volatile("s_waitcnt vmcnt(0)" ::: "memory");
        __builtin_amdgcn_sched_barrier(0);
        const int b8 = 8 * tid;
        sH[par][swzH_pos(b8 + 0)] = r0[0]; sH[par][swzH_pos(b8 + 1)] = r0[1];
        sH[par][swzH_pos(b8 + 2)] = r1[0]; sH[par][swzH_pos(b8 + 3)] = r1[1];
        sH[par][swzH_pos(b8 + 4)] = r2[0]; sH[par][swzH_pos(b8 + 5)] = r2[1];
        sH[par][swzH_pos(b8 + 6)] = r3[0]; sH[par][swzH_pos(b8 + 7)] = r3[1];
      } else {
        const int b8 = 8 * tid;
        #pragma unroll
        for (int j = 0; j < 8; ++j) sH[par][swzH_pos(b8 + j)] = 0u;
      }
    }
    __syncthreads();                                   // barrier 1

    // ---- row dots (register weights x LDS operand) ----
    float a0 = 0, a1 = 0, a2 = 0, a3 = 0, a4 = 0, a5 = 0;
    if (G < 16) {                                      // Wh groups: h[s-1]
      const u32x4* HV = (const u32x4*)sH[par];
      #pragma unroll
      for (int c = 0; c < 8; ++c) {
        const u32x4 h4 = HV[8 * q + (c ^ (q & 7))];
        MAC4(a0, wv[0][c], h4); MAC4(a1, wv[1][c], h4); MAC4(a2, wv[2][c], h4);
        MAC4(a3, wv[3][c], h4); MAC4(a4, wv[4][c], h4); MAC4(a5, wv[5][c], h4);
      }
    } else if (role != 0) {                            // Wi groups: stream
      const u32x4* IV = (const u32x4*)sIN[s & 7];
      #pragma unroll
      for (int c = 0; c < 8; ++c) {
        const u32x4 h4 = IV[8 * q + (c ^ (q & 7))];
        MAC4(a0, wv[0][c], h4); MAC4(a1, wv[1][c], h4); MAC4(a2, wv[2][c], h4);
        MAC4(a3, wv[3][c], h4); MAC4(a4, wv[4][c], h4); MAC4(a5, wv[5][c], h4);
      }
    } else {                                           // role0 Wi: x (512 col)
      const u32x4* XV = (const u32x4*)sX[s & 7];
      #pragma unroll
      for (int c = 0; c < 4; ++c) {
        const int ch = 4 * q + c;
        const u32x4 h4 = XV[ch ^ ((ch >> 2) & 7)];
        MAC4(a0, wv[0][c], h4); MAC4(a1, wv[1][c], h4); MAC4(a2, wv[2][c], h4);
        MAC4(a3, wv[3][c], h4); MAC4(a4, wv[4][c], h4); MAC4(a5, wv[5][c], h4);
      }
    }
    RED16(a0); RED16(a1); RED16(a2); RED16(a3); RED16(a4); RED16(a5);
    if (q < 6) {
      const float v = (q == 0) ? a0 : (q == 1) ? a1 : (q == 2) ? a2
                    : (q == 3) ? a3 : (q == 4) ? a4 : a5;
      if (G < 16) sD[G * 6 + q] = v;
      else        sDI[(G - 16) * 6 + q] = v;
    }
    __syncthreads();                                   // barrier 2

    // ---- gate combine + publish (lanes 0..31 of wave 0) ----
    if (tid < 32) {
      const float rg = sigf(sDI[tid] + bIr + sD[tid] + bHr);
      const float zg = sigf(sDI[32 + tid] + bIz + sD[32 + tid] + bHz);
      const float ng = tanh_f(sDI[64 + tid] + bIn + rg * (sD[64 + tid] + bHn));
      const int ge = e0 + tid;
      const float hp = unpk(sH[par][swzH_pos(ge >> 1)], ge & 1);
      const float hn = (1.f - zg) * ng + zg * hp;
      // shuffles with all 32 source lanes active (r8-proven); store guarded.
      const int b4 = (tid & 7) * 4;
      const float v0 = __shfl(hn, b4),     v1 = __shfl(hn, b4 + 1);
      const float v2 = __shfl(hn, b4 + 2), v3 = __shfl(hn, b4 + 3);
      if (tid < 8) {
        u32x4 rec = {pk(v0, v1), pk(v2, v3), (unsigned)s, 0u};
        st_sc_v4(&outA[s][rank * 8 + tid], rec);
      }
    }
    // next iter's barrier1 orders all buffer reuse
  }

  // =======================  FC tail (role 3, rank 0)  ========================
  if (role == 3 && rank == 0) {
    if (tid < 256) {                    // h2_0[255] -> sH[0]
      const u32x4* a = &g_q0s[S2 - 1][tid];
      u32x4 r = ld_sc_v4(a);
      while (r[2] != (unsigned)(S2 - 1)) { __builtin_amdgcn_s_sleep(8); r = ld_sc_v4(a); }
      sH[0][swzH_pos(2 * tid)]     = r[0];
      sH[0][swzH_pos(2 * tid + 1)] = r[1];
    } else {                            // h2_1[255] -> sH[1]
      const u32x4* a = &g_q1s[S2 - 1][rid];
      u32x4 r = ld_sc_v4(a);
      while (r[2] != (unsigned)(S2 - 1)) { __builtin_amdgcn_s_sleep(8); r = ld_sc_v4(a); }
      sH[1][swzH_pos(2 * rid)]     = r[0];
      sH[1][swzH_pos(2 * rid + 1)] = r[1];
    }
    __syncthreads();
    if (tid < 128) {
      const int l = tid >> 6, k = tid & 63;
      const unsigned* Hs = (const unsigned*)sH[l];
      const float* wrow = fc1W + (size_t)k * 1024;
      float acc = fc1b[k];
      for (int j2 = 0; j2 < 512; ++j2) {
        const unsigned hu = Hs[swzH_pos(j2)];
        acc += unpk(hu, 0) * wrow[2 * j2] + unpk(hu, 1) * wrow[2 * j2 + 1];
      }
      sY[tid] = sigf(acc);
    }
    __syncthreads();
    if (tid < 2) {
      const float* yv = sY + tid * 64;
      float acc = fc2b[0];
      for (int k2 = 0; k2 < 64; ++k2) acc += fc2W[k2] * yv[k2];
      out[tid] = sigf(acc);
    }
  }
}

extern "C" void kernel_launch(void* const* d_in, const int* in_sizes, int n_in,
                              void* d_out, int out_size, void* d_ws, size_t ws_size,
                              hipStream_t stream) {
  (void)in_sizes; (void)n_in; (void)out_size; (void)d_ws; (void)ws_size;
  const float* x      = (const float*)d_in[0];
  const float* g1_Wi0 = (const float*)d_in[1];
  const float* g1_Wh0 = (const float*)d_in[2];
  const float* g1_bi0 = (const float*)d_in[3];
  const float* g1_bh0 = (const float*)d_in[4];
  const float* g1_Wi1 = (const float*)d_in[5];
  const float* g1_Wh1 = (const float*)d_in[6];
  const float* g1_bi1 = (const float*)d_in[7];
  const float* g1_bh1 = (const float*)d_in[8];
  const float* g2_Wi0 = (const float*)d_in[9];
  const float* g2_Wh0 = (const float*)d_in[10];
  const float* g2_bi0 = (const float*)d_in[11];
  const float* g2_bh0 = (const float*)d_in[12];
  const float* g2_Wi1 = (const float*)d_in[13];
  const float* g2_Wh1 = (const float*)d_in[14];
  const float* g2_bi1 = (const float*)d_in[15];
  const float* g2_bh1 = (const float*)d_in[16];
  const float* fc1W   = (const float*)d_in[17];
  const float* fc1b   = (const float*)d_in[18];
  const float* fc2W   = (const float*)d_in[19];
  const float* fc2b   = (const float*)d_in[20];
  float* out = (float*)d_out;

  init_all<<<dim3(2048), dim3(256), 0, stream>>>();
  gru_all<<<dim3(256), dim3(512), 0, stream>>>(
      x, g1_Wi0, g1_Wh0, g1_bi0, g1_bh0, g1_Wi1, g1_Wh1, g1_bi1, g1_bh1,
      g2_Wi0, g2_Wh0, g2_bi0, g2_bh0, g2_Wi1, g2_Wh1, g2_bi1, g2_bh1,
      fc1W, fc1b, fc2W, fc2b, out);
}

// Round 16
// 25519.609 us; speedup vs baseline: 2.4386x; 1.1529x over previous
//
#include <hip/hip_runtime.h>

// ---------------------------------------------------------------------------
// GRUNet, round 16: REVERT to round-13 (measured best, 25.36ms).
// Campaign summary (r1-r15): the kernel is latency-bound on 8448 sequential
// rounds x cross-CU broadcast. Nine sync-protocol variants (sc1 poll, relay,
// per-XCD domains, sc0 local publish, atomic64 records, parallel stream RTTs,
// single-poller counter, pipelined non-blocking poll) all land at 25.4-62ms.
// Floor arithmetic: per round = 3072x1024 f16 matvec over >=16 CUs (~0.4us)
// + 32-CU all-to-all 4KB broadcast via MALL (measured >=2.5us; 2-party
// primitive floor 0.72us, r11). 8448 x 2.9us ~= 24.5ms ~= achieved 25.36ms.
// Single-CU recurrence costs 5us/step compute (worse); the scan is nonlinear
// (unbatchable). This revision = r13 verbatim.
// ---------------------------------------------------------------------------

typedef unsigned u32x4 __attribute__((ext_vector_type(4)));
typedef _Float16 h2_t  __attribute__((ext_vector_type(2)));

#define S1 8192
#define S2 256

__device__ u32x4 g_h0s[S1][256];   // history records {pair0,pair1,tag,0} (sc1)
__device__ u32x4 g_h1s[S1][256];
__device__ u32x4 g_q0s[S2][256];
__device__ u32x4 g_q1s[S2][256];
__device__ unsigned long long g_fast[4][2][512];  // {seq:32 | 2xf16:32}
__device__ int   g_claim[128];     // 4 roles x 32 slices

// ---- f16 pack/unpack ----
__device__ __forceinline__ unsigned pk(float a, float b) {
  unsigned short ua = __builtin_bit_cast(unsigned short, (_Float16)a);
  unsigned short ub = __builtin_bit_cast(unsigned short, (_Float16)b);
  return (unsigned)ua | ((unsigned)ub << 16);
}
__device__ __forceinline__ float unpk(unsigned u, int hi) {
  unsigned short us = (unsigned short)(hi ? (u >> 16) : (u & 0xffffu));
  return (float)__builtin_bit_cast(_Float16, us);
}

#if __has_builtin(__builtin_amdgcn_fdot2)
__device__ __forceinline__ float fdot2(unsigned a, unsigned b, float c) {
  return __builtin_amdgcn_fdot2(__builtin_bit_cast(h2_t, a),
                                __builtin_bit_cast(h2_t, b), c, false);
}
#else
__device__ __forceinline__ float fdot2(unsigned a, unsigned b, float c) {
  h2_t ha = __builtin_bit_cast(h2_t, a), hb = __builtin_bit_cast(h2_t, b);
  return c + (float)ha[0] * (float)hb[0] + (float)ha[1] * (float)hb[1];
}
#endif

// ---- sc1 (MALL-coherent) loads/stores ----
__device__ __forceinline__ u32x4 ld_sc_v4(const u32x4* p) {
  u32x4 v;
  asm volatile("global_load_dwordx4 %0, %1, off sc1\n\t"
               "s_waitcnt vmcnt(0)" : "=&v"(v) : "v"(p) : "memory");
  return v;
}
// 4 loads issued back-to-back, ONE wait: 1 RTT instead of 4.
__device__ __forceinline__ void ld_sc_4x4(const u32x4* p0, const u32x4* p1,
                                          const u32x4* p2, const u32x4* p3,
                                          u32x4& a, u32x4& b, u32x4& c, u32x4& d) {
  asm volatile("global_load_dwordx4 %0, %4, off sc1\n\t"
               "global_load_dwordx4 %1, %5, off sc1\n\t"
               "global_load_dwordx4 %2, %6, off sc1\n\t"
               "global_load_dwordx4 %3, %7, off sc1\n\t"
               "s_waitcnt vmcnt(0)"
               : "=&v"(a), "=&v"(b), "=&v"(c), "=&v"(d)
               : "v"(p0), "v"(p1), "v"(p2), "v"(p3) : "memory");
}
__device__ __forceinline__ void st_sc_v4(u32x4* p, u32x4 v) {
  asm volatile("global_store_dwordx4 %0, %1, off sc1" :: "v"(p), "v"(v) : "memory");
}

// ---- fast activations ----
__device__ __forceinline__ float rcpf(float x) {
#if __has_builtin(__builtin_amdgcn_rcpf)
  return __builtin_amdgcn_rcpf(x);
#else
  return 1.f / x;
#endif
}
__device__ __forceinline__ float sigf(float x) { return rcpf(1.f + __expf(-x)); }
__device__ __forceinline__ float tanh_f(float x) {
  x = fminf(fmaxf(x, -15.f), 15.f);
  const float e = __expf(2.f * x);
  return (e - 1.f) * rcpf(e + 1.f);
}

// ---- LDS swizzles ----
__device__ __forceinline__ int swzHc(int ch) { return ch ^ ((ch >> 3) & 7); }
__device__ __forceinline__ int swzH_pos(int i) { return (swzHc(i >> 2) << 2) | (i & 3); }
__device__ __forceinline__ int swzX_pos(int i) {
  int ch = i >> 2; ch ^= (ch >> 2) & 7; return (ch << 2) | (i & 3);
}

__global__ void init_all() {
  const long long NH = (long long)S1 * 256;
  const long long NQ = (long long)S2 * 256;
  const long long N  = 2 * NH + 2 * NQ;
  u32x4 ff = {0u, 0u, 0xFFFFFFFFu, 0u};
  const long long idx = (long long)blockIdx.x * blockDim.x + threadIdx.x;
  const long long str = (long long)gridDim.x * blockDim.x;
  for (long long k = idx; k < N; k += str) {
    u32x4* r;
    long long k2 = k;
    if (k2 < NH) r = &g_h0s[0][0] + k2;
    else {
      k2 -= NH;
      if (k2 < NH) r = &g_h1s[0][0] + k2;
      else {
        k2 -= NH;
        if (k2 < NQ) r = &g_q0s[0][0] + k2;
        else         r = &g_q1s[0][0] + (k2 - NQ);
      }
    }
    *r = ff;
  }
  for (long long k = idx; k < 4LL * 2 * 512; k += str)
    ((unsigned long long*)g_fast)[k] = 0xFFFFFFFF00000000ULL;
  if (blockIdx.x == 0 && threadIdx.x < 128) g_claim[threadIdx.x] = 0;
}

__device__ __forceinline__ const u32x4* in_addr(int role, int u, int r) {
  if (role == 1) return &g_h0s[u][r];
  if (role == 2) {
    const int ss = ((u >> 1) << 6) + 63;
    return (u & 1) ? &g_h1s[ss][r] : &g_h0s[ss][r];
  }
  return &g_q0s[u][r];
}
__device__ __forceinline__ unsigned in_want(int role, int u) {
  return (role == 2) ? (unsigned)(((u >> 1) << 6) + 63) : (unsigned)u;
}

#define MAC4(A, W4, H4)                                                       \
  A = fdot2((W4)[0], (H4)[0], A); A = fdot2((W4)[1], (H4)[1], A);             \
  A = fdot2((W4)[2], (H4)[2], A); A = fdot2((W4)[3], (H4)[3], A);

#define RED16(A)                                                              \
  A += __shfl_xor(A, 8, 16); A += __shfl_xor(A, 4, 16);                       \
  A += __shfl_xor(A, 2, 16); A += __shfl_xor(A, 1, 16);

// One wave fetches ALL 256 records of stream step u (4 recs/lane, 1 RTT),
// blocking-repoll until tags match, then stages into sIN[u&7].
#define STREAM_FETCH_WAVE(U, LN)                                              \
  {                                                                           \
    const unsigned w = in_want(role, (U));                                    \
    const u32x4* p0 = in_addr(role, (U), 4 * (LN) + 0);                       \
    const u32x4* p1 = in_addr(role, (U), 4 * (LN) + 1);                       \
    const u32x4* p2 = in_addr(role, (U), 4 * (LN) + 2);                       \
    const u32x4* p3 = in_addr(role, (U), 4 * (LN) + 3);                       \
    u32x4 r0, r1, r2, r3;                                                     \
    ld_sc_4x4(p0, p1, p2, p3, r0, r1, r2, r3);                                \
    while (r0[2] != w || r1[2] != w || r2[2] != w || r3[2] != w)              \
      ld_sc_4x4(p0, p1, p2, p3, r0, r1, r2, r3);                              \
    unsigned* dst = sIN[(U) & 7];                                             \
    const int b8 = 8 * (LN);                                                  \
    dst[swzH_pos(b8 + 0)] = r0[0]; dst[swzH_pos(b8 + 1)] = r0[1];             \
    dst[swzH_pos(b8 + 2)] = r1[0]; dst[swzH_pos(b8 + 3)] = r1[1];             \
    dst[swzH_pos(b8 + 4)] = r2[0]; dst[swzH_pos(b8 + 5)] = r2[1];             \
    dst[swzH_pos(b8 + 6)] = r3[0]; dst[swzH_pos(b8 + 7)] = r3[1];             \
  }

// One wave fetches the full 512-float x row of step u (8 floats/lane).
#define X_FETCH_WAVE(U, LN)                                                   \
  {                                                                           \
    const float4* xp = (const float4*)(x +                                    \
        (size_t)(((U) & 63) * 128 + ((U) >> 6)) * 512 + 8 * (LN));            \
    float4 a = xp[0], b = xp[1];                                              \
    unsigned* dst = sX[(U) & 7];                                              \
    const int b4 = 4 * (LN);                                                  \
    dst[swzX_pos(b4 + 0)] = pk(a.x, a.y);                                     \
    dst[swzX_pos(b4 + 1)] = pk(a.z, a.w);                                     \
    dst[swzX_pos(b4 + 2)] = pk(b.x, b.y);                                     \
    dst[swzX_pos(b4 + 3)] = pk(b.z, b.w);                                     \
  }

__global__
__attribute__((amdgpu_flat_work_group_size(512, 512), amdgpu_waves_per_eu(2, 2)))
void gru_all(const float* __restrict__ x,
             const float* __restrict__ g1_Wi0, const float* __restrict__ g1_Wh0,
             const float* __restrict__ g1_bi0, const float* __restrict__ g1_bh0,
             const float* __restrict__ g1_Wi1, const float* __restrict__ g1_Wh1,
             const float* __restrict__ g1_bi1, const float* __restrict__ g1_bh1,
             const float* __restrict__ g2_Wi0, const float* __restrict__ g2_Wh0,
             const float* __restrict__ g2_bi0, const float* __restrict__ g2_bh0,
             const float* __restrict__ g2_Wi1, const float* __restrict__ g2_Wh1,
             const float* __restrict__ g2_bi1, const float* __restrict__ g2_bh1,
             const float* __restrict__ fc1W, const float* __restrict__ fc1b,
             const float* __restrict__ fc2W, const float* __restrict__ fc2b,
             float* __restrict__ out)
{
  const int tid = threadIdx.x;
  const int G   = tid >> 4;            // 32 groups of 16 lanes
  const int q   = tid & 15;
  const int sw  = (tid >> 6) - 4;      // stream-wave id 0..3 (tid>=256)
  const int ln  = tid & 63;            // lane in wave
  const int rid = tid - 256;

  __shared__ __attribute__((aligned(16))) unsigned sH[2][512];   // own h[s-1]
  __shared__ __attribute__((aligned(16))) unsigned sIN[8][512];  // stream ring
  __shared__ __attribute__((aligned(16))) unsigned sX[8][256];   // x ring (role0)
  __shared__ float sD[96];             // Wh row dots
  __shared__ float sDI[96];            // Wi row dots
  __shared__ float sY[128];
  __shared__ int   sSlot;

  // ---- slot claim: prefer own-XCD role; bounded global fallback ----
  unsigned xcc;
  asm volatile("s_getreg_b32 %0, hwreg(HW_REG_XCC_ID)" : "=s"(xcc));
  xcc &= 7u;
  if (tid == 0) {
    int slot = -1;
    if (xcc < 4u) {
      for (int i = 0; i < 32 && slot < 0; ++i)
        if (atomicCAS(&g_claim[(int)xcc * 32 + i], 0, 1) == 0)
          slot = (int)xcc * 32 + i;
    }
    if (slot < 0) {
      for (int k = 0; k < 32; ++k) __builtin_amdgcn_s_sleep(64);  // ~60us
      for (int i = 0; i < 128 && slot < 0; ++i)
        if (atomicCAS(&g_claim[i], 0, 1) == 0) slot = i;
    }
    sSlot = slot;
  }
  __syncthreads();
  const int slot = sSlot;
  if (slot < 0) return;                // surplus WG
  const int role = slot >> 5;          // 0..3
  const int rank = slot & 31;          // h-slice [32*rank, +32)
  const int e0   = rank * 32;
  const int S    = (role <= 1) ? S1 : S2;

  const float* Wh  = (role == 0) ? g1_Wh0 : (role == 1) ? g1_Wh1
                   : (role == 2) ? g2_Wh0 : g2_Wh1;
  const float* Wi  = (role == 0) ? g1_Wi0 : (role == 1) ? g1_Wi1
                   : (role == 2) ? g2_Wi0 : g2_Wi1;
  const float* pbi = (role == 0) ? g1_bi0 : (role == 1) ? g1_bi1
                   : (role == 2) ? g2_bi0 : g2_bi1;
  const float* pbh = (role == 0) ? g1_bh0 : (role == 1) ? g1_bh1
                   : (role == 2) ? g2_bh0 : g2_bh1;
  u32x4 (*outA)[256] = (role == 0) ? g_h0s : (role == 1) ? g_h1s
                     : (role == 2) ? g_q0s : g_q1s;

  // ---- weights -> registers: group (G) owns 6 rows of ONE matrix ----
  u32x4 wv[6][8];
  {
    const bool isWh = (G < 16);
    const int  Gm   = isWh ? G : (G - 16);
    const float* M  = isWh ? Wh : Wi;
    const bool wide = isWh || (role != 0);
    #pragma unroll
    for (int j = 0; j < 6; ++j) {
      const int rr = Gm * 6 + j;
      const int R  = (rr >> 5) * 1024 + e0 + (rr & 31);
      if (wide) {
        const float4* rp = (const float4*)(M + (size_t)R * 1024 + 64 * q);
        #pragma unroll
        for (int c = 0; c < 8; ++c) {
          float4 a = rp[2 * c], b = rp[2 * c + 1];
          wv[j][c] = (u32x4){pk(a.x, a.y), pk(a.z, a.w), pk(b.x, b.y), pk(b.z, b.w)};
        }
      } else {
        const float4* rp = (const float4*)(M + (size_t)R * 512 + 32 * q);
        #pragma unroll
        for (int c = 0; c < 4; ++c) {
          float4 a = rp[2 * c], b = rp[2 * c + 1];
          wv[j][c] = (u32x4){pk(a.x, a.y), pk(a.z, a.w), pk(b.x, b.y), pk(b.z, b.w)};
        }
      }
    }
  }

  // ---- biases for combine lanes (tid<32 -> elem e0+tid) ----
  float bIr = 0, bIz = 0, bIn = 0, bHr = 0, bHz = 0, bHn = 0;
  if (tid < 32) {
    const int ge = e0 + tid;
    bIr = pbi[ge]; bIz = pbi[1024 + ge]; bIn = pbi[2048 + ge];
    bHr = pbh[ge]; bHz = pbh[1024 + ge]; bHn = pbh[2048 + ge];
  }

  // ---- stream prologue: wave 4+k fetches step k (parallel across waves) ----
  if (tid >= 256) {
    const int u = sw;                  // 0..3 (< S always)
    if (role == 0) { X_FETCH_WAVE(u, ln); }
    else           { STREAM_FETCH_WAVE(u, ln); }
  }
  __syncthreads();

  // =======================  serial scan  =======================
  for (int s = 0; s < S; ++s) {
    const int par = s & 1;

    // ---- stream batch-fetch: wave 4+k owns step s+4+k (1 parallel RTT) ----
    if (tid >= 256 && (s & 3) == 0) {
      const int u = s + 4 + sw;
      if (u < S) {
        if (role == 0) { X_FETCH_WAVE(u, ln); }
        else           { STREAM_FETCH_WAVE(u, ln); }
      }
    }

    // ---- own recurrence poll: atomic64 records (data+seq in one op) ----
    if (tid < 256) {
      unsigned d0 = 0, d1 = 0;
      if (s > 0) {
        const unsigned w = (unsigned)(s - 1);
        unsigned long long* f0 = &g_fast[role][(s - 1) & 1][2 * tid];
        unsigned long long* f1 = f0 + 1;
        unsigned long long v0 = atomicAdd(f0, 0ull);
        unsigned long long v1 = atomicAdd(f1, 0ull);
        bool o0 = ((unsigned)(v0 >> 32) == w), o1 = ((unsigned)(v1 >> 32) == w);
        while (!(o0 && o1)) {
          if (!o0) v0 = atomicAdd(f0, 0ull);
          if (!o1) v1 = atomicAdd(f1, 0ull);
          o0 = ((unsigned)(v0 >> 32) == w); o1 = ((unsigned)(v1 >> 32) == w);
        }
        d0 = (unsigned)v0; d1 = (unsigned)v1;
      }
      sH[par][swzH_pos(2 * tid)]     = d0;
      sH[par][swzH_pos(2 * tid + 1)] = d1;
    }
    __syncthreads();                                   // barrier 1

    // ---- row dots (register weights x LDS operand) ----
    float a0 = 0, a1 = 0, a2 = 0, a3 = 0, a4 = 0, a5 = 0;
    if (G < 16) {                                      // Wh groups: h[s-1]
      const u32x4* HV = (const u32x4*)sH[par];
      #pragma unroll
      for (int c = 0; c < 8; ++c) {
        const u32x4 h4 = HV[8 * q + (c ^ (q & 7))];
        MAC4(a0, wv[0][c], h4); MAC4(a1, wv[1][c], h4); MAC4(a2, wv[2][c], h4);
        MAC4(a3, wv[3][c], h4); MAC4(a4, wv[4][c], h4); MAC4(a5, wv[5][c], h4);
      }
    } else if (role != 0) {                            // Wi groups: stream
      const u32x4* IV = (const u32x4*)sIN[s & 7];
      #pragma unroll
      for (int c = 0; c < 8; ++c) {
        const u32x4 h4 = IV[8 * q + (c ^ (q & 7))];
        MAC4(a0, wv[0][c], h4); MAC4(a1, wv[1][c], h4); MAC4(a2, wv[2][c], h4);
        MAC4(a3, wv[3][c], h4); MAC4(a4, wv[4][c], h4); MAC4(a5, wv[5][c], h4);
      }
    } else {                                           // role0 Wi: x (512 col)
      const u32x4* XV = (const u32x4*)sX[s & 7];
      #pragma unroll
      for (int c = 0; c < 4; ++c) {
        const int ch = 4 * q + c;
        const u32x4 h4 = XV[ch ^ ((ch >> 2) & 7)];
        MAC4(a0, wv[0][c], h4); MAC4(a1, wv[1][c], h4); MAC4(a2, wv[2][c], h4);
        MAC4(a3, wv[3][c], h4); MAC4(a4, wv[4][c], h4); MAC4(a5, wv[5][c], h4);
      }
    }
    RED16(a0); RED16(a1); RED16(a2); RED16(a3); RED16(a4); RED16(a5);
    if (q < 6) {
      const float v = (q == 0) ? a0 : (q == 1) ? a1 : (q == 2) ? a2
                    : (q == 3) ? a3 : (q == 4) ? a4 : a5;
      if (G < 16) sD[G * 6 + q] = v;
      else        sDI[(G - 16) * 6 + q] = v;
    }
    __syncthreads();                                   // barrier 2

    // ---- gate combine + publish (lanes 0..31 of wave 0) ----
    if (tid < 32) {
      const float rg = sigf(sDI[tid] + bIr + sD[tid] + bHr);
      const float zg = sigf(sDI[32 + tid] + bIz + sD[32 + tid] + bHz);
      const float ng = tanh_f(sDI[64 + tid] + bIn + rg * (sD[64 + tid] + bHn));
      const int ge = e0 + tid;
      const float hp = unpk(sH[par][swzH_pos(ge >> 1)], ge & 1);
      const float hn = (1.f - zg) * ng + zg * hp;
      // shuffles with all 32 source lanes active (r8-proven); stores guarded.
      const int i2 = (tid & 15) * 2;
      const float p0 = __shfl(hn, i2), p1 = __shfl(hn, i2 + 1);
      const int b4 = (tid & 7) * 4;
      const float v0 = __shfl(hn, b4),     v1 = __shfl(hn, b4 + 1);
      const float v2 = __shfl(hn, b4 + 2), v3 = __shfl(hn, b4 + 3);
      if (tid < 16) {                                  // fast path FIRST
        unsigned long long val =
            ((unsigned long long)(unsigned)s << 32) | (unsigned long long)pk(p0, p1);
        atomicExch(&g_fast[role][s & 1][rank * 16 + tid], val);
      }
      if (tid < 8) {                                   // history/stream (sc1)
        u32x4 rec = {pk(v0, v1), pk(v2, v3), (unsigned)s, 0u};
        st_sc_v4(&outA[s][rank * 8 + tid], rec);
      }
    }
    // next iter's barrier1 orders all buffer reuse
  }

  // =======================  FC tail (role 3, rank 0)  ========================
  if (role == 3 && rank == 0) {
    if (tid < 256) {                    // h2_0[255] -> sH[0]
      const u32x4* a = &g_q0s[S2 - 1][tid];
      u32x4 r = ld_sc_v4(a);
      while (r[2] != (unsigned)(S2 - 1)) r = ld_sc_v4(a);
      sH[0][swzH_pos(2 * tid)]     = r[0];
      sH[0][swzH_pos(2 * tid + 1)] = r[1];
    } else {                            // h2_1[255] -> sH[1]
      const u32x4* a = &g_q1s[S2 - 1][rid];
      u32x4 r = ld_sc_v4(a);
      while (r[2] != (unsigned)(S2 - 1)) r = ld_sc_v4(a);
      sH[1][swzH_pos(2 * rid)]     = r[0];
      sH[1][swzH_pos(2 * rid + 1)] = r[1];
    }
    __syncthreads();
    if (tid < 128) {
      const int l = tid >> 6, k = tid & 63;
      const unsigned* Hs = (const unsigned*)sH[l];
      const float* wrow = fc1W + (size_t)k * 1024;
      float acc = fc1b[k];
      for (int j2 = 0; j2 < 512; ++j2) {
        const unsigned hu = Hs[swzH_pos(j2)];
        acc += unpk(hu, 0) * wrow[2 * j2] + unpk(hu, 1) * wrow[2 * j2 + 1];
      }
      sY[tid] = sigf(acc);
    }
    __syncthreads();
    if (tid < 2) {
      const float* yv = sY + tid * 64;
      float acc = fc2b[0];
      for (int k2 = 0; k2 < 64; ++k2) acc += fc2W[k2] * yv[k2];
      out[tid] = sigf(acc);
    }
  }
}

extern "C" void kernel_launch(void* const* d_in, const int* in_sizes, int n_in,
                              void* d_out, int out_size, void* d_ws, size_t ws_size,
                              hipStream_t stream) {
  (void)in_sizes; (void)n_in; (void)out_size; (void)d_ws; (void)ws_size;
  const float* x      = (const float*)d_in[0];
  const float* g1_Wi0 = (const float*)d_in[1];
  const float* g1_Wh0 = (const float*)d_in[2];
  const float* g1_bi0 = (const float*)d_in[3];
  const float* g1_bh0 = (const float*)d_in[4];
  const float* g1_Wi1 = (const float*)d_in[5];
  const float* g1_Wh1 = (const float*)d_in[6];
  const float* g1_bi1 = (const float*)d_in[7];
  const float* g1_bh1 = (const float*)d_in[8];
  const float* g2_Wi0 = (const float*)d_in[9];
  const float* g2_Wh0 = (const float*)d_in[10];
  const float* g2_bi0 = (const float*)d_in[11];
  const float* g2_bh0 = (const float*)d_in[12];
  const float* g2_Wi1 = (const float*)d_in[13];
  const float* g2_Wh1 = (const float*)d_in[14];
  const float* g2_bi1 = (const float*)d_in[15];
  const float* g2_bh1 = (const float*)d_in[16];
  const float* fc1W   = (const float*)d_in[17];
  const float* fc1b   = (const float*)d_in[18];
  const float* fc2W   = (const float*)d_in[19];
  const float* fc2b   = (const float*)d_in[20];
  float* out = (float*)d_out;

  init_all<<<dim3(2048), dim3(256), 0, stream>>>();
  gru_all<<<dim3(256), dim3(512), 0, stream>>>(
      x, g1_Wi0, g1_Wh0, g1_bi0, g1_bh0, g1_Wi1, g1_Wh1, g1_bi1, g1_bh1,
      g2_Wi0, g2_Wh0, g2_bi0, g2_bh0, g2_Wi1, g2_Wh1, g2_bi1, g2_bh1,
      fc1W, fc1b, fc2W, fc2b, out);
}